// Round 5
// baseline (192.482 us; speedup 1.0000x reference)
//
#include <hip/hip_runtime.h>
#include <math.h>

// Problem constants (match reference)
constexpr int B_ = 32;
constexpr int C_ = 32;
constexpr int RES_ = 16;
constexpr int G_ = RES_ * RES_ * RES_;   // 4096
constexpr int N_ = 16384;
constexpr int H_ = 64;
// sqrt(3)/RES
__device__ constexpr float REG_THR = 0.10825317547305483f;

// float -> bf16 bits, round-to-nearest-even (values are finite here).
__device__ __forceinline__ unsigned short f2bf(float f) {
    union { float f; unsigned int u; } v; v.f = f;
    const unsigned int r = v.u + 0x7FFFu + ((v.u >> 16) & 1u);
    return (unsigned short)(r >> 16);
}

// ---------------------------------------------------------------------------
// Kernel 1: per-batch inclusive scan of counts (4096 cells) -> cum[b][G].
// (R8's proven scan; bounded work regardless of input values.)
// ---------------------------------------------------------------------------
__global__ __launch_bounds__(256) void scan_kernel(const int* __restrict__ counts,
                                                   int* __restrict__ cum) {
    const int b = blockIdx.x;
    const int* cb = counts + b * G_;
    int* ob = cum + b * G_;

    __shared__ int partials[256];
    const int t = threadIdx.x;
    const int base = t * 16;

    int local[16];
    int s = 0;
#pragma unroll
    for (int i = 0; i < 16; ++i) {
        s += cb[base + i];
        local[i] = s;
    }
    partials[t] = s;
    __syncthreads();

    for (int off = 1; off < 256; off <<= 1) {
        int v = (t >= off) ? partials[t - off] : 0;
        __syncthreads();
        partials[t] += v;
        __syncthreads();
    }
    const int prev = (t > 0) ? partials[t - 1] : 0;

#pragma unroll
    for (int i = 0; i < 16; ++i) ob[base + i] = prev + local[i];
}

// ---------------------------------------------------------------------------
// Kernel 2 (R13, fused A+B): per 128-cell tile,
//   phase 1: s_hx[cell][h] = bf16(b1[h] + sum_c W1[h,c]*x[b,c,cell]) in LDS
//            (R12's proven hx phase: packed bf16 pairs, RS=33 bank-safe,
//             wave-uniform weight broadcasts, 2 cells/thread)
//   phase 2: slots are sorted by cell, so this tile owns the CONTIGUOUS
//            point range [cum[tile-1], cum[tile+127]). For each k in range:
//            branchless 7-step lower-bound over the 128 local cum entries
//            (always in-bounds), read hx from LDS, finish the MLP + reg.
// hxb global round-trip (16.8 MB write + 67 MB gathered read-back) and the
// third kernel launch are GONE. Workspace use: cum only (512 KB).
// Poison-safety: all loops bounded (k-loop <= N/256 iters; search 7 iters,
// reads clamped in-bounds; writes only to [0,N) slots of out/reg).
// ---------------------------------------------------------------------------
constexpr int TCELL = 128;    // cells per block (2 per thread in phase 1)
constexpr int RS = 33;        // s_hx row stride in uints (odd: bank-safe)
constexpr int WROW = 36;      // W1 LDS row stride (floats)

__global__ __launch_bounds__(256, 4) void fused_kernel(
    const float* __restrict__ x, const float* __restrict__ W1,
    const float* __restrict__ b1, const float* __restrict__ b_rnd,
    const float* __restrict__ W2, const float* __restrict__ b2,
    const int* __restrict__ cum, float* __restrict__ out0,
    float* __restrict__ reg_out) {
    const int b = blockIdx.y;
    const int tile = blockIdx.x * TCELL;
    const int t = threadIdx.x;

    __shared__ float __align__(16) s_w1[H_ * WROW];   // 9.2 KB
    __shared__ unsigned int s_hx[TCELL * RS];         // 16.9 KB
    __shared__ int s_lc[TCELL];                       // 0.5 KB
    __shared__ int s_kb;

    // Stage the tile's cum slice early (overlaps with weight/x loads).
    if (t < TCELL) s_lc[t] = cum[b * G_ + tile + t];
    if (t == TCELL) s_kb = (tile == 0) ? 0 : cum[b * G_ + tile - 1];

    // Cooperative W1 fill (2176 floats) + b1 into the row pad.
    for (int i = t; i < H_ * 34; i += 256) {
        const int r = i / 34;
        const int c = i - r * 34;
        s_w1[r * WROW + c] = W1[i];
    }
    if (t < H_) s_w1[t * WROW + 34] = b1[t];

    // Coalesced x loads for BOTH cells (issued before barrier: overlap HBM).
    const int cell_l = t & 63;
    const int hh2 = __builtin_amdgcn_readfirstlane((t >> 6) * 8); // uint idx
    const float* xb = x + ((size_t)b * C_) * G_ + tile + cell_l;
    float xv0[C_], xv1[C_];
#pragma unroll
    for (int c = 0; c < C_; ++c) {
        xv0[c] = xb[(size_t)c * G_];
        xv1[c] = xb[(size_t)c * G_ + 64];
    }
    __syncthreads();

    // Phase 1: 8 h-pairs per thread x 2 cells; wave-uniform weight broadcasts.
    unsigned int* row0 = s_hx + cell_l * RS + hh2;
    unsigned int* row1 = s_hx + (cell_l + 64) * RS + hh2;
#pragma unroll 2
    for (int j = 0; j < 8; ++j) {
        const float* we = s_w1 + (2 * (hh2 + j) + 0) * WROW;
        const float* wo = s_w1 + (2 * (hh2 + j) + 1) * WROW;
        float e0 = we[34], q0 = wo[34];        // b1[h]
        float e1 = e0,     q1 = q0;
#pragma unroll
        for (int c = 0; c < C_; ++c) {
            e0 = fmaf(we[c], xv0[c], e0);
            q0 = fmaf(wo[c], xv0[c], q0);
            e1 = fmaf(we[c], xv1[c], e1);
            q1 = fmaf(wo[c], xv1[c], q1);
        }
        // bank = (cell*33 + k)%32 = (cell + k)%32 across lanes: conflict-free
        row0[j] = (unsigned int)f2bf(e0) | ((unsigned int)f2bf(q0) << 16);
        row1[j] = (unsigned int)f2bf(e1) | ((unsigned int)f2bf(q1) << 16);
    }
    __syncthreads();

    // Phase 2: this tile's contiguous point range.
    int kb = s_kb;            kb = kb < 0 ? 0 : (kb > N_ ? N_ : kb);
    int ke = s_lc[TCELL - 1]; ke = ke < kb ? kb : (ke > N_ ? N_ : ke);

    const float* r0p = b_rnd + ((size_t)b * 2 + 0) * N_;
    const float* r1p = b_rnd + ((size_t)b * 2 + 1) * N_;
    float* p0 = out0 + ((size_t)b * 3) * N_;
    float* rg = reg_out + (size_t)b * N_;

    for (int k = kb + t; k < ke; k += 256) {
        // Branchless lower-bound: pos = #entries with s_lc[i] <= k.
        // Probe index pos+st-1 is provably <= 127 at every step.
        int pos = 0;
#pragma unroll
        for (int st = 64; st > 0; st >>= 1)
            if (s_lc[pos + st - 1] <= k) pos += st;
        // real inputs guarantee pos<=127 (s_lc[127]>k); clamp for poison
        const int loc = pos < TCELL - 1 ? pos : TCELL - 1;
        const int cellg = tile + loc;

        const float r0 = r0p[k];
        const float r1 = r1p[k];
        const unsigned int* hp = s_hx + loc * RS;

        float o0 = b2[0], o1 = b2[1], o2 = b2[2];
#pragma unroll
        for (int g = 0; g < 8; ++g) {          // 8 h per group, 4 uints
            unsigned int uw[4];
#pragma unroll
            for (int q = 0; q < 4; ++q) uw[q] = hp[g * 4 + q];
            float hvv[8];
#pragma unroll
            for (int q = 0; q < 4; ++q) {
                union { unsigned int u; float f; } a, bwd;
                a.u = uw[q] << 16;             // even h
                bwd.u = uw[q] & 0xFFFF0000u;   // odd h
                hvv[2 * q] = a.f;
                hvv[2 * q + 1] = bwd.f;
            }
#pragma unroll
            for (int j = 0; j < 8; ++j) {
                const int h = g * 8 + j;
                float hv = hvv[j];
                hv = fmaf(W1[h * 34 + 32], r0, hv);
                hv = fmaf(W1[h * 34 + 33], r1, hv);
                hv = fmaxf(hv, 0.0f);
                o0 = fmaf(W2[0 * H_ + h], hv, o0);
                o1 = fmaf(W2[1 * H_ + h], hv, o1);
                o2 = fmaf(W2[2 * H_ + h], hv, o2);
            }
        }

        const float nrm = sqrtf(o0 * o0 + o1 * o1 + o2 * o2);
        const float reg = fmaxf(nrm - REG_THR, 0.0f);

        // grid_o[d][cell] = (i_d + 0.5)/16 - 0.5, exact in fp32 from bits.
        o0 += (float)((cellg >> 8) & 15) * 0.0625f - 0.46875f;
        o1 += (float)((cellg >> 4) & 15) * 0.0625f - 0.46875f;
        o2 += (float)(cellg & 15) * 0.0625f - 0.46875f;

        p0[k]              = o0;
        p0[N_ + k]         = o1;
        p0[2 * (size_t)N_ + k] = o2;
        rg[k] = reg;
    }
}

// ---------------------------------------------------------------------------
extern "C" void kernel_launch(void* const* d_in, const int* in_sizes, int n_in,
                              void* d_out, int out_size, void* d_ws, size_t ws_size,
                              hipStream_t stream) {
    const float* x      = (const float*)d_in[0];  // (B, C, RES, RES, RES)
    const int*   counts = (const int*)  d_in[1];  // (B, G)
    const float* b_rnd  = (const float*)d_in[2];  // (B, 2, N)
    // d_in[3] = grid_o: unused (recomputed exactly from idx bits)
    const float* W1     = (const float*)d_in[4];  // (H, C+2)
    const float* b1     = (const float*)d_in[5];  // (H,)
    const float* W2     = (const float*)d_in[6];  // (3, H)
    const float* b2     = (const float*)d_in[7];  // (3,)

    float* out  = (float*)d_out;                  // (B, 3, N) then (B, N)
    float* rout = out + (size_t)B_ * 3 * N_;

    int* cum = (int*)d_ws;                        // B*G ints = 512 KB

    scan_kernel<<<B_, 256, 0, stream>>>(counts, cum);

    dim3 gridF(G_ / TCELL, B_);                   // (32, 32) = 1024 blocks
    fused_kernel<<<gridF, 256, 0, stream>>>(x, W1, b1, b_rnd, W2, b2,
                                            cum, out, rout);
}

// Round 6
// 121.152 us; speedup vs baseline: 1.5888x; 1.5888x over previous
//
#include <hip/hip_runtime.h>
#include <math.h>

// Problem constants (match reference)
constexpr int B_ = 32;
constexpr int C_ = 32;
constexpr int RES_ = 16;
constexpr int G_ = RES_ * RES_ * RES_;   // 4096
constexpr int N_ = 16384;
constexpr int H_ = 64;
// sqrt(3)/RES
__device__ constexpr float REG_THR = 0.10825317547305483f;

// float -> bf16 bits, round-to-nearest-even (values are finite here).
__device__ __forceinline__ unsigned short f2bf(float f) {
    union { float f; unsigned int u; } v; v.f = f;
    const unsigned int r = v.u + 0x7FFFu + ((v.u >> 16) & 1u);
    return (unsigned short)(r >> 16);
}

// ---------------------------------------------------------------------------
// Kernel 1: per-batch inclusive scan of counts (4096 cells) -> cum[b][G].
// ---------------------------------------------------------------------------
__global__ __launch_bounds__(256) void scan_kernel(const int* __restrict__ counts,
                                                   int* __restrict__ cum) {
    const int b = blockIdx.x;
    const int* cb = counts + b * G_;
    int* ob = cum + b * G_;

    __shared__ int partials[256];
    const int t = threadIdx.x;
    const int base = t * 16;

    int local[16];
    int s = 0;
#pragma unroll
    for (int i = 0; i < 16; ++i) {
        s += cb[base + i];
        local[i] = s;
    }
    partials[t] = s;
    __syncthreads();

    for (int off = 1; off < 256; off <<= 1) {
        int v = (t >= off) ? partials[t - off] : 0;
        __syncthreads();
        partials[t] += v;
        __syncthreads();
    }
    const int prev = (t > 0) ? partials[t - 1] : 0;

#pragma unroll
    for (int i = 0; i < 16; ++i) ob[base + i] = prev + local[i];
}

// ---------------------------------------------------------------------------
// Kernel 2 (fused A+B): per 128-cell tile,
//   phase 1: s_hx[cell][h] = bf16(b1[h] + sum_c W1[h,c]*x[b,c,cell]) in LDS
//   phase 2: slots are sorted by cell -> this tile owns the CONTIGUOUS point
//            range [cum[tile-1], cum[tile+127]); branchless 7-step
//            lower-bound over the 128 local cum entries; hx read from LDS;
//            finish MLP + reg. No hxb global round-trip, no third kernel.
//
// R14 FIX: __launch_bounds__(256) — R13's (256, 4) min-waves/EU floor capped
// the allocator at VGPR_Count=64, spilling xv0[32]+xv1[32] to scratch (HBM):
// counters showed 337 MB traffic vs ~30 MB ideal, fused dur 119 us ~= 337 MB
// / 2.8 TB/s. One-token fix; everything else identical to R13.
//
// Poison-safety: all loops bounded (k-loop <= N/256 iters; search 7 iters,
// reads clamped in-bounds; writes only to [0,N) slots of out/reg).
// ---------------------------------------------------------------------------
constexpr int TCELL = 128;    // cells per block (2 per thread in phase 1)
constexpr int RS = 33;        // s_hx row stride in uints (odd: bank-safe)
constexpr int WROW = 36;      // W1 LDS row stride (floats)

__global__ __launch_bounds__(256) void fused_kernel(
    const float* __restrict__ x, const float* __restrict__ W1,
    const float* __restrict__ b1, const float* __restrict__ b_rnd,
    const float* __restrict__ W2, const float* __restrict__ b2,
    const int* __restrict__ cum, float* __restrict__ out0,
    float* __restrict__ reg_out) {
    const int b = blockIdx.y;
    const int tile = blockIdx.x * TCELL;
    const int t = threadIdx.x;

    __shared__ float __align__(16) s_w1[H_ * WROW];   // 9.2 KB
    __shared__ unsigned int s_hx[TCELL * RS];         // 16.9 KB
    __shared__ int s_lc[TCELL];                       // 0.5 KB
    __shared__ int s_kb;

    // Stage the tile's cum slice early (overlaps with weight/x loads).
    if (t < TCELL) s_lc[t] = cum[b * G_ + tile + t];
    if (t == TCELL) s_kb = (tile == 0) ? 0 : cum[b * G_ + tile - 1];

    // Cooperative W1 fill (2176 floats) + b1 into the row pad.
    for (int i = t; i < H_ * 34; i += 256) {
        const int r = i / 34;
        const int c = i - r * 34;
        s_w1[r * WROW + c] = W1[i];
    }
    if (t < H_) s_w1[t * WROW + 34] = b1[t];

    // Coalesced x loads for BOTH cells (issued before barrier: overlap HBM).
    const int cell_l = t & 63;
    const int hh2 = __builtin_amdgcn_readfirstlane((t >> 6) * 8); // uint idx
    const float* xb = x + ((size_t)b * C_) * G_ + tile + cell_l;
    float xv0[C_], xv1[C_];
#pragma unroll
    for (int c = 0; c < C_; ++c) {
        xv0[c] = xb[(size_t)c * G_];
        xv1[c] = xb[(size_t)c * G_ + 64];
    }
    __syncthreads();

    // Phase 1: 8 h-pairs per thread x 2 cells; wave-uniform weight broadcasts.
    unsigned int* row0 = s_hx + cell_l * RS + hh2;
    unsigned int* row1 = s_hx + (cell_l + 64) * RS + hh2;
#pragma unroll 2
    for (int j = 0; j < 8; ++j) {
        const float* we = s_w1 + (2 * (hh2 + j) + 0) * WROW;
        const float* wo = s_w1 + (2 * (hh2 + j) + 1) * WROW;
        float e0 = we[34], q0 = wo[34];        // b1[h]
        float e1 = e0,     q1 = q0;
#pragma unroll
        for (int c = 0; c < C_; ++c) {
            e0 = fmaf(we[c], xv0[c], e0);
            q0 = fmaf(wo[c], xv0[c], q0);
            e1 = fmaf(we[c], xv1[c], e1);
            q1 = fmaf(wo[c], xv1[c], q1);
        }
        // bank = (cell*33 + k)%32 = (cell + k)%32 across lanes: conflict-free
        row0[j] = (unsigned int)f2bf(e0) | ((unsigned int)f2bf(q0) << 16);
        row1[j] = (unsigned int)f2bf(e1) | ((unsigned int)f2bf(q1) << 16);
    }
    __syncthreads();

    // Phase 2: this tile's contiguous point range.
    int kb = s_kb;            kb = kb < 0 ? 0 : (kb > N_ ? N_ : kb);
    int ke = s_lc[TCELL - 1]; ke = ke < kb ? kb : (ke > N_ ? N_ : ke);

    const float* r0p = b_rnd + ((size_t)b * 2 + 0) * N_;
    const float* r1p = b_rnd + ((size_t)b * 2 + 1) * N_;
    float* p0 = out0 + ((size_t)b * 3) * N_;
    float* rg = reg_out + (size_t)b * N_;

    for (int k = kb + t; k < ke; k += 256) {
        // Branchless lower-bound: pos = #entries with s_lc[i] <= k.
        int pos = 0;
#pragma unroll
        for (int st = 64; st > 0; st >>= 1)
            if (s_lc[pos + st - 1] <= k) pos += st;
        // real inputs guarantee pos<=127 (s_lc[127]>k); clamp for poison
        const int loc = pos < TCELL - 1 ? pos : TCELL - 1;
        const int cellg = tile + loc;

        const float r0 = r0p[k];
        const float r1 = r1p[k];
        const unsigned int* hp = s_hx + loc * RS;

        float o0 = b2[0], o1 = b2[1], o2 = b2[2];
#pragma unroll
        for (int g = 0; g < 8; ++g) {          // 8 h per group, 4 uints
            unsigned int uw[4];
#pragma unroll
            for (int q = 0; q < 4; ++q) uw[q] = hp[g * 4 + q];
            float hvv[8];
#pragma unroll
            for (int q = 0; q < 4; ++q) {
                union { unsigned int u; float f; } a, bwd;
                a.u = uw[q] << 16;             // even h
                bwd.u = uw[q] & 0xFFFF0000u;   // odd h
                hvv[2 * q] = a.f;
                hvv[2 * q + 1] = bwd.f;
            }
#pragma unroll
            for (int j = 0; j < 8; ++j) {
                const int h = g * 8 + j;
                float hv = hvv[j];
                hv = fmaf(W1[h * 34 + 32], r0, hv);
                hv = fmaf(W1[h * 34 + 33], r1, hv);
                hv = fmaxf(hv, 0.0f);
                o0 = fmaf(W2[0 * H_ + h], hv, o0);
                o1 = fmaf(W2[1 * H_ + h], hv, o1);
                o2 = fmaf(W2[2 * H_ + h], hv, o2);
            }
        }

        const float nrm = sqrtf(o0 * o0 + o1 * o1 + o2 * o2);
        const float reg = fmaxf(nrm - REG_THR, 0.0f);

        // grid_o[d][cell] = (i_d + 0.5)/16 - 0.5, exact in fp32 from bits.
        o0 += (float)((cellg >> 8) & 15) * 0.0625f - 0.46875f;
        o1 += (float)((cellg >> 4) & 15) * 0.0625f - 0.46875f;
        o2 += (float)(cellg & 15) * 0.0625f - 0.46875f;

        p0[k]              = o0;
        p0[N_ + k]         = o1;
        p0[2 * (size_t)N_ + k] = o2;
        rg[k] = reg;
    }
}

// ---------------------------------------------------------------------------
extern "C" void kernel_launch(void* const* d_in, const int* in_sizes, int n_in,
                              void* d_out, int out_size, void* d_ws, size_t ws_size,
                              hipStream_t stream) {
    const float* x      = (const float*)d_in[0];  // (B, C, RES, RES, RES)
    const int*   counts = (const int*)  d_in[1];  // (B, G)
    const float* b_rnd  = (const float*)d_in[2];  // (B, 2, N)
    // d_in[3] = grid_o: unused (recomputed exactly from idx bits)
    const float* W1     = (const float*)d_in[4];  // (H, C+2)
    const float* b1     = (const float*)d_in[5];  // (H,)
    const float* W2     = (const float*)d_in[6];  // (3, H)
    const float* b2     = (const float*)d_in[7];  // (3,)

    float* out  = (float*)d_out;                  // (B, 3, N) then (B, N)
    float* rout = out + (size_t)B_ * 3 * N_;

    int* cum = (int*)d_ws;                        // B*G ints = 512 KB

    scan_kernel<<<B_, 256, 0, stream>>>(counts, cum);

    dim3 gridF(G_ / TCELL, B_);                   // (32, 32) = 1024 blocks
    fused_kernel<<<gridF, 256, 0, stream>>>(x, W1, b1, b_rnd, W2, b2,
                                            cum, out, rout);
}

// Round 7
// 108.668 us; speedup vs baseline: 1.7713x; 1.1149x over previous
//
#include <hip/hip_runtime.h>
#include <math.h>

// Problem constants (match reference)
constexpr int B_ = 32;
constexpr int C_ = 32;
constexpr int RES_ = 16;
constexpr int G_ = RES_ * RES_ * RES_;   // 4096
constexpr int N_ = 16384;
constexpr int H_ = 64;
// sqrt(3)/RES
__device__ constexpr float REG_THR = 0.10825317547305483f;

// float -> bf16 bits, round-to-nearest-even (values are finite here).
__device__ __forceinline__ unsigned short f2bf(float f) {
    union { float f; unsigned int u; } v; v.f = f;
    const unsigned int r = v.u + 0x7FFFu + ((v.u >> 16) & 1u);
    return (unsigned short)(r >> 16);
}

// ---------------------------------------------------------------------------
// Kernel A (fused): hx compute + per-batch scan/scatter.
// R15 = R10's proven split structure (109.9 us) + R11's packed-bf16 s_hx
// (LDS 42.5 -> 26 KB: 6 blocks/CU vs 3; LDS instr halved) + clamped scatter.
// R13/R14's full fusion REVERTED: measured 67-72 us at 19% occupancy vs
// ~33 us for the split pipeline (R12 double-launch measurement) — the
// 1024-block no-refill grid + per-block barrier coupling + 7-step dependent
// LDS search made it latency-bound. Split kernels run barrier-free at
// 2048/1056 blocks.
// ---------------------------------------------------------------------------
constexpr int TCELL = 128;    // cells per block (2 per thread)
constexpr int RS = 33;        // s_hx row stride in uints (odd: bank-safe)
constexpr int WROW = 36;      // W1 LDS row stride (floats)

__global__ __launch_bounds__(256) void hx_scan_kernel(
    const float* __restrict__ x, const float* __restrict__ W1,
    const float* __restrict__ b1, const int* __restrict__ counts,
    unsigned short* __restrict__ hxb, int* __restrict__ idxarr) {
    const int b = blockIdx.y;
    const int t = threadIdx.x;

    __shared__ float __align__(16) s_w1[H_ * WROW];   // 9.2 KB
    __shared__ unsigned int s_hx[TCELL * RS];         // 16.9 KB

    if (blockIdx.x == G_ / TCELL) {
        // ---- scan + scatter (one block per batch) ----
        int* partials = (int*)s_w1;                   // 1 KB alias
        const int* cb = counts + b * G_;
        const int base = t * 16;
        int local[16];
        int s = 0;
#pragma unroll
        for (int i = 0; i < 16; ++i) { s += cb[base + i]; local[i] = s; }
        partials[t] = s;
        __syncthreads();
        for (int off = 1; off < 256; off <<= 1) {
            int v = (t >= off) ? partials[t - off] : 0;
            __syncthreads();
            partials[t] += v;
            __syncthreads();
        }
        const int prev = (t > 0) ? partials[t - 1] : 0;

        int* ib = idxarr + b * N_;
        int startk = prev;
#pragma unroll
        for (int i = 0; i < 16; ++i) {
            const int endk = prev + local[i];
            const int cell = base + i;
            const int k0 = startk > 0 ? startk : 0;        // poison-safe
            const int k1 = endk < N_ ? endk : N_;
            for (int k = k0; k < k1; ++k) ib[k] = cell;
            startk = endk;
        }
        return;
    }

    // ---- hx branch ----
    const int tile = blockIdx.x * TCELL;
    const int cell_l = t & 63;                 // lane = cell (within half-tile)
    const int hh2 = __builtin_amdgcn_readfirstlane((t >> 6) * 8); // uint idx

    // Cooperative W1 fill (2176 floats) + b1 into the row pad.
    for (int i = t; i < H_ * 34; i += 256) {
        const int r = i / 34;
        const int c = i - r * 34;
        s_w1[r * WROW + c] = W1[i];
    }
    if (t < H_) s_w1[t * WROW + 34] = b1[t];

    // Coalesced x loads for BOTH cells (issued before barrier: overlap HBM).
    const float* xb = x + ((size_t)b * C_) * G_ + tile + cell_l;
    float xv0[C_], xv1[C_];
#pragma unroll
    for (int c = 0; c < C_; ++c) {
        xv0[c] = xb[(size_t)c * G_];
        xv1[c] = xb[(size_t)c * G_ + 64];
    }
    __syncthreads();

    // 8 h-pairs per thread x 2 cells; weight-row broadcasts feed 4 FMAs/c.
    unsigned int* row0 = s_hx + cell_l * RS + hh2;
    unsigned int* row1 = s_hx + (cell_l + 64) * RS + hh2;
#pragma unroll 2
    for (int j = 0; j < 8; ++j) {
        const float* we = s_w1 + (2 * (hh2 + j) + 0) * WROW;
        const float* wo = s_w1 + (2 * (hh2 + j) + 1) * WROW;
        float e0 = we[34], q0 = wo[34];        // b1[h]
        float e1 = e0,     q1 = q0;
#pragma unroll
        for (int c = 0; c < C_; ++c) {
            e0 = fmaf(we[c], xv0[c], e0);
            q0 = fmaf(wo[c], xv0[c], q0);
            e1 = fmaf(we[c], xv1[c], e1);
            q1 = fmaf(wo[c], xv1[c], q1);
        }
        // bank = (cell*33 + k)%32 = (cell + k)%32 across lanes: conflict-free
        row0[j] = (unsigned int)f2bf(e0) | ((unsigned int)f2bf(q0) << 16);
        row1[j] = (unsigned int)f2bf(e1) | ((unsigned int)f2bf(q1) << 16);
    }
    __syncthreads();

    // Copy-out: already bf16-packed; linear coalesced uint4 stores.
    uint4* ob4 = (uint4*)(hxb + ((size_t)b * G_ + tile) * H_);
#pragma unroll
    for (int k = 0; k < 4; ++k) {
        const int L4 = t + k * 256;            // uint4 index (8 bf16)
        const int cell = L4 >> 3;
        const int base = (L4 & 7) * 4;         // uint offset within cell
        const unsigned int* s = s_hx + cell * RS + base;
        ob4[L4] = make_uint4(s[0], s[1], s[2], s[3]);
    }
}

// ---------------------------------------------------------------------------
// Kernel B: one thread per (b, n) point.  (R10's proven kernel + idx clamp)
//   idx = idxarr[b][n]   (precomputed scatter; no LDS, no binary search)
//   W1/W2/b2 reads stay uniform-address global loads -> s_load + K$ (R9's
//   LDS table was measured +5 us: don't move them onto the LDS pipe).
//   idx clamped to [0, G): under poison, unwritten idxarr slots hold
//   garbage; unclamped they'd index hxb far out of bounds.
// ---------------------------------------------------------------------------
__global__ __launch_bounds__(256) void point_kernel(
    const unsigned short* __restrict__ hxb, const float* __restrict__ b_rnd,
    const float* __restrict__ W1, const float* __restrict__ W2,
    const float* __restrict__ b2, const int* __restrict__ idxarr,
    float* __restrict__ out0, float* __restrict__ reg_out) {
    const int b = blockIdx.y;
    const int n = blockIdx.x * 256 + threadIdx.x;

    int idx = idxarr[(size_t)b * N_ + n];
    idx = idx < 0 ? 0 : (idx > G_ - 1 ? G_ - 1 : idx);   // poison-safe
    const float r0 = b_rnd[((size_t)b * 2 + 0) * N_ + n];
    const float r1 = b_rnd[((size_t)b * 2 + 1) * N_ + n];
    const unsigned short* hp = hxb + ((size_t)b * G_ + idx) * H_;

    float o0 = b2[0], o1 = b2[1], o2 = b2[2];
#pragma unroll
    for (int g = 0; g < 8; ++g) {              // 8 h per group, one uint4
        const uint4 u = *(const uint4*)(hp + g * 8);
        const unsigned int uw[4] = {u.x, u.y, u.z, u.w};
        float hvv[8];
#pragma unroll
        for (int q = 0; q < 4; ++q) {
            union { unsigned int u; float f; } a, bwd;
            a.u = uw[q] << 16;                 // even h
            bwd.u = uw[q] & 0xFFFF0000u;       // odd h
            hvv[2 * q] = a.f;
            hvv[2 * q + 1] = bwd.f;
        }
#pragma unroll
        for (int j = 0; j < 8; ++j) {
            const int h = g * 8 + j;
            float hv = hvv[j];
            hv = fmaf(W1[h * 34 + 32], r0, hv);
            hv = fmaf(W1[h * 34 + 33], r1, hv);
            hv = fmaxf(hv, 0.0f);
            o0 = fmaf(W2[0 * H_ + h], hv, o0);
            o1 = fmaf(W2[1 * H_ + h], hv, o1);
            o2 = fmaf(W2[2 * H_ + h], hv, o2);
        }
    }

    const float nrm = sqrtf(o0 * o0 + o1 * o1 + o2 * o2);
    const float reg = fmaxf(nrm - REG_THR, 0.0f);

    // grid_o[k][idx] = (i_k + 0.5)/16 - 0.5, exact in fp32 from idx bits.
    o0 += (float)((idx >> 8) & 15) * 0.0625f - 0.46875f;
    o1 += (float)((idx >> 4) & 15) * 0.0625f - 0.46875f;
    o2 += (float)(idx & 15) * 0.0625f - 0.46875f;

    float* p = out0 + ((size_t)b * 3) * N_ + n;
    p[0]              = o0;
    p[N_]             = o1;
    p[2 * (size_t)N_] = o2;
    reg_out[(size_t)b * N_ + n] = reg;
}

// ---------------------------------------------------------------------------
extern "C" void kernel_launch(void* const* d_in, const int* in_sizes, int n_in,
                              void* d_out, int out_size, void* d_ws, size_t ws_size,
                              hipStream_t stream) {
    const float* x      = (const float*)d_in[0];  // (B, C, RES, RES, RES)
    const int*   counts = (const int*)  d_in[1];  // (B, G)
    const float* b_rnd  = (const float*)d_in[2];  // (B, 2, N)
    // d_in[3] = grid_o: unused (recomputed exactly from idx bits)
    const float* W1     = (const float*)d_in[4];  // (H, C+2)
    const float* b1     = (const float*)d_in[5];  // (H,)
    const float* W2     = (const float*)d_in[6];  // (3, H)
    const float* b2     = (const float*)d_in[7];  // (3,)

    float* out  = (float*)d_out;                  // (B, 3, N) then (B, N)
    float* rout = out + (size_t)B_ * 3 * N_;

    int* idxarr = (int*)d_ws;                     // B*N ints = 2 MB
    unsigned short* hxb =
        (unsigned short*)((char*)d_ws + (size_t)B_ * N_ * sizeof(int));
                                                  // B*G*H bf16 = 16.8 MB

    dim3 gridA(G_ / TCELL + 1, B_);               // (33, 32): +1 col = scan
    dim3 gridB(N_ / 256, B_);

    hx_scan_kernel<<<gridA, 256, 0, stream>>>(x, W1, b1, counts, hxb, idxarr);
    point_kernel<<<gridB, 256, 0, stream>>>(hxb, b_rnd, W1, W2, b2,
                                            idxarr, out, rout);
}

// Round 8
// 104.748 us; speedup vs baseline: 1.8376x; 1.0374x over previous
//
#include <hip/hip_runtime.h>
#include <math.h>

// Problem constants (match reference)
constexpr int B_ = 32;
constexpr int C_ = 32;
constexpr int RES_ = 16;
constexpr int G_ = RES_ * RES_ * RES_;   // 4096
constexpr int N_ = 16384;
constexpr int H_ = 64;
// sqrt(3)/RES
__device__ constexpr float REG_THR = 0.10825317547305483f;

typedef __attribute__((ext_vector_type(2))) float v2f;

__device__ __forceinline__ v2f fma2(v2f a, v2f b, v2f c) {
    return __builtin_elementwise_fma(a, b, c);
}

// float -> bf16 bits, round-to-nearest-even (values are finite here).
__device__ __forceinline__ unsigned short f2bf(float f) {
    union { float f; unsigned int u; } v; v.f = f;
    const unsigned int r = v.u + 0x7FFFu + ((v.u >> 16) & 1u);
    return (unsigned short)(r >> 16);
}

// ---------------------------------------------------------------------------
// Kernel A (fused): hx compute + per-batch scan/scatter.
// R15 structure (split pipeline, 108.7 us best) + R16 packed-fp32 inner
// loop: the fp32 vector peak (157.3 TF) is only reachable via v_pk_fma_f32
// (2 FMA/inst); scalar fmaf runs at half rate. Pair over the CHANNEL dim:
// weight pair = one 8B LDS b64 broadcast (also halves LDS instr count), x
// pairs live in VGPRs. 1024 scalar FMA/thread -> 512 pk + 32 h-adds.
// ---------------------------------------------------------------------------
constexpr int TCELL = 128;    // cells per block (2 per thread)
constexpr int RS = 33;        // s_hx row stride in uints (odd: bank-safe)
constexpr int WROW = 36;      // W1 LDS row stride (floats; row base 8B-aligned)

__global__ __launch_bounds__(256) void hx_scan_kernel(
    const float* __restrict__ x, const float* __restrict__ W1,
    const float* __restrict__ b1, const int* __restrict__ counts,
    unsigned short* __restrict__ hxb, int* __restrict__ idxarr) {
    const int b = blockIdx.y;
    const int t = threadIdx.x;

    __shared__ float __align__(16) s_w1[H_ * WROW];   // 9.2 KB
    __shared__ unsigned int s_hx[TCELL * RS];         // 16.9 KB

    if (blockIdx.x == G_ / TCELL) {
        // ---- scan + scatter (one block per batch) ----
        int* partials = (int*)s_w1;                   // 1 KB alias
        const int* cb = counts + b * G_;
        const int base = t * 16;
        int local[16];
        int s = 0;
#pragma unroll
        for (int i = 0; i < 16; ++i) { s += cb[base + i]; local[i] = s; }
        partials[t] = s;
        __syncthreads();
        for (int off = 1; off < 256; off <<= 1) {
            int v = (t >= off) ? partials[t - off] : 0;
            __syncthreads();
            partials[t] += v;
            __syncthreads();
        }
        const int prev = (t > 0) ? partials[t - 1] : 0;

        int* ib = idxarr + b * N_;
        int startk = prev;
#pragma unroll
        for (int i = 0; i < 16; ++i) {
            const int endk = prev + local[i];
            const int cell = base + i;
            const int k0 = startk > 0 ? startk : 0;        // poison-safe
            const int k1 = endk < N_ ? endk : N_;
            for (int k = k0; k < k1; ++k) ib[k] = cell;
            startk = endk;
        }
        return;
    }

    // ---- hx branch ----
    const int tile = blockIdx.x * TCELL;
    const int cell_l = t & 63;                 // lane = cell (within half-tile)
    const int hh2 = __builtin_amdgcn_readfirstlane((t >> 6) * 8); // uint idx

    // Cooperative W1 fill (2176 floats) + b1 into the row pad.
    for (int i = t; i < H_ * 34; i += 256) {
        const int r = i / 34;
        const int c = i - r * 34;
        s_w1[r * WROW + c] = W1[i];
    }
    if (t < H_) s_w1[t * WROW + 34] = b1[t];

    // Coalesced x loads for BOTH cells, packed as channel pairs.
    const float* xb = x + ((size_t)b * C_) * G_ + tile + cell_l;
    v2f xv0[C_ / 2], xv1[C_ / 2];
#pragma unroll
    for (int c2 = 0; c2 < C_ / 2; ++c2) {
        xv0[c2].x = xb[(size_t)(2 * c2 + 0) * G_];
        xv0[c2].y = xb[(size_t)(2 * c2 + 1) * G_];
        xv1[c2].x = xb[(size_t)(2 * c2 + 0) * G_ + 64];
        xv1[c2].y = xb[(size_t)(2 * c2 + 1) * G_ + 64];
    }
    __syncthreads();

    // 8 h-pairs per thread x 2 cells; packed-fp32 FMA over channel pairs.
    unsigned int* row0 = s_hx + cell_l * RS + hh2;
    unsigned int* row1 = s_hx + (cell_l + 64) * RS + hh2;
#pragma unroll 2
    for (int j = 0; j < 8; ++j) {
        const float* we = s_w1 + (2 * (hh2 + j) + 0) * WROW;
        const float* wo = s_w1 + (2 * (hh2 + j) + 1) * WROW;
        v2f e0p = {0.f, 0.f}, q0p = {0.f, 0.f};
        v2f e1p = {0.f, 0.f}, q1p = {0.f, 0.f};
#pragma unroll
        for (int c2 = 0; c2 < C_ / 2; ++c2) {
            const v2f wep = *(const v2f*)(we + 2 * c2);   // b64 broadcast
            const v2f wop = *(const v2f*)(wo + 2 * c2);
            e0p = fma2(wep, xv0[c2], e0p);
            q0p = fma2(wop, xv0[c2], q0p);
            e1p = fma2(wep, xv1[c2], e1p);
            q1p = fma2(wop, xv1[c2], q1p);
        }
        const float e0 = we[34] + e0p.x + e0p.y;          // + b1[h]
        const float q0 = wo[34] + q0p.x + q0p.y;
        const float e1 = we[34] + e1p.x + e1p.y;
        const float q1 = wo[34] + q1p.x + q1p.y;
        // bank = (cell*33 + k)%32 = (cell + k)%32 across lanes: conflict-free
        row0[j] = (unsigned int)f2bf(e0) | ((unsigned int)f2bf(q0) << 16);
        row1[j] = (unsigned int)f2bf(e1) | ((unsigned int)f2bf(q1) << 16);
    }
    __syncthreads();

    // Copy-out: already bf16-packed; linear coalesced uint4 stores.
    uint4* ob4 = (uint4*)(hxb + ((size_t)b * G_ + tile) * H_);
#pragma unroll
    for (int k = 0; k < 4; ++k) {
        const int L4 = t + k * 256;            // uint4 index (8 bf16)
        const int cell = L4 >> 3;
        const int base = (L4 & 7) * 4;         // uint offset within cell
        const unsigned int* s = s_hx + cell * RS + base;
        ob4[L4] = make_uint4(s[0], s[1], s[2], s[3]);
    }
}

// ---------------------------------------------------------------------------
// Kernel B: one thread per (b, n) point.
//   idx = idxarr[b][n] & (G-1)   (poison-safe, 1 op)
//   Layer 1 stays SCALAR fmaf (packing it would need per-h v_mov dup of the
//   non-contiguous W1 coefficient pairs — no win). ReLU + layer 2 are
//   PACKED: hv even/odd pairs fall out of the bf16 unpack naturally, and
//   W2[o][h..h+1] is a contiguous 64-bit uniform operand (VOP3P-legal
//   single scalar source). W1/W2/b2 stay uniform-address global loads
//   (R9 measured: do NOT move them onto the LDS pipe).
// ---------------------------------------------------------------------------
__global__ __launch_bounds__(256) void point_kernel(
    const unsigned short* __restrict__ hxb, const float* __restrict__ b_rnd,
    const float* __restrict__ W1, const float* __restrict__ W2,
    const float* __restrict__ b2, const int* __restrict__ idxarr,
    float* __restrict__ out0, float* __restrict__ reg_out) {
    const int b = blockIdx.y;
    const int n = blockIdx.x * 256 + threadIdx.x;

    const int idx = idxarr[(size_t)b * N_ + n] & (G_ - 1);   // poison-safe
    const float r0 = b_rnd[((size_t)b * 2 + 0) * N_ + n];
    const float r1 = b_rnd[((size_t)b * 2 + 1) * N_ + n];
    const unsigned short* hp = hxb + ((size_t)b * G_ + idx) * H_;

    v2f o0p = {0.f, 0.f}, o1p = {0.f, 0.f}, o2p = {0.f, 0.f};
    const v2f zz = {0.f, 0.f};
#pragma unroll
    for (int g = 0; g < 8; ++g) {              // 8 h per group, one uint4
        const uint4 u = *(const uint4*)(hp + g * 8);
        const unsigned int uw[4] = {u.x, u.y, u.z, u.w};
#pragma unroll
        for (int q = 0; q < 4; ++q) {
            const int h = g * 8 + 2 * q;       // even h of the pair
            union { unsigned int u; float f; } a, bwd;
            a.u = uw[q] << 16;                 // even h
            bwd.u = uw[q] & 0xFFFF0000u;       // odd h
            // Layer 1: scalar (non-contiguous W1 pairs)
            float he = a.f, ho = bwd.f;
            he = fmaf(W1[h * 34 + 32], r0, he);
            he = fmaf(W1[h * 34 + 33], r1, he);
            ho = fmaf(W1[(h + 1) * 34 + 32], r0, ho);
            ho = fmaf(W1[(h + 1) * 34 + 33], r1, ho);
            // ReLU + layer 2: packed
            v2f hv2; hv2.x = he; hv2.y = ho;
            hv2 = __builtin_elementwise_max(hv2, zz);
            o0p = fma2(*(const v2f*)(W2 + 0 * H_ + h), hv2, o0p);
            o1p = fma2(*(const v2f*)(W2 + 1 * H_ + h), hv2, o1p);
            o2p = fma2(*(const v2f*)(W2 + 2 * H_ + h), hv2, o2p);
        }
    }
    float o0 = b2[0] + o0p.x + o0p.y;
    float o1 = b2[1] + o1p.x + o1p.y;
    float o2 = b2[2] + o2p.x + o2p.y;

    const float nrm = sqrtf(o0 * o0 + o1 * o1 + o2 * o2);
    const float reg = fmaxf(nrm - REG_THR, 0.0f);

    // grid_o[k][idx] = (i_k + 0.5)/16 - 0.5, exact in fp32 from idx bits.
    o0 += (float)((idx >> 8) & 15) * 0.0625f - 0.46875f;
    o1 += (float)((idx >> 4) & 15) * 0.0625f - 0.46875f;
    o2 += (float)(idx & 15) * 0.0625f - 0.46875f;

    float* p = out0 + ((size_t)b * 3) * N_ + n;
    p[0]              = o0;
    p[N_]             = o1;
    p[2 * (size_t)N_] = o2;
    reg_out[(size_t)b * N_ + n] = reg;
}

// ---------------------------------------------------------------------------
extern "C" void kernel_launch(void* const* d_in, const int* in_sizes, int n_in,
                              void* d_out, int out_size, void* d_ws, size_t ws_size,
                              hipStream_t stream) {
    const float* x      = (const float*)d_in[0];  // (B, C, RES, RES, RES)
    const int*   counts = (const int*)  d_in[1];  // (B, G)
    const float* b_rnd  = (const float*)d_in[2];  // (B, 2, N)
    // d_in[3] = grid_o: unused (recomputed exactly from idx bits)
    const float* W1     = (const float*)d_in[4];  // (H, C+2)
    const float* b1     = (const float*)d_in[5];  // (H,)
    const float* W2     = (const float*)d_in[6];  // (3, H)
    const float* b2     = (const float*)d_in[7];  // (3,)

    float* out  = (float*)d_out;                  // (B, 3, N) then (B, N)
    float* rout = out + (size_t)B_ * 3 * N_;

    int* idxarr = (int*)d_ws;                     // B*N ints = 2 MB
    unsigned short* hxb =
        (unsigned short*)((char*)d_ws + (size_t)B_ * N_ * sizeof(int));
                                                  // B*G*H bf16 = 16.8 MB

    dim3 gridA(G_ / TCELL + 1, B_);               // (33, 32): +1 col = scan
    dim3 gridB(N_ / 256, B_);

    hx_scan_kernel<<<gridA, 256, 0, stream>>>(x, W1, b1, counts, hxb, idxarr);
    point_kernel<<<gridB, 256, 0, stream>>>(hxb, b_rnd, W1, W2, b2,
                                            idxarr, out, rout);
}